// Round 8
// baseline (108.842 us; speedup 1.0000x reference)
//
#include <hip/hip_runtime.h>

// Problem constants (from reference): B=16, C=1, H=768, W=768, K=512
#define BDIM 16
#define HDIM 768
#define WDIM 768
#define KCOR 512
#define STRIP 8                           // rows per strip block
constexpr int HW = HDIM * WDIM;           // 589824
constexpr int QW = WDIM / 4;              // 192 float4 quads per row (= block size)
constexpr int STRIPS = HDIM / STRIP;      // 96 strips per image
constexpr int NSTRIPB = BDIM * STRIPS;    // 1536 strip blocks
constexpr int NCORRB = BDIM;              // 16 corr blocks (first in grid)
constexpr int NBLK = NSTRIPB + NCORRB;    // 1552 total

typedef float f4v __attribute__((ext_vector_type(4)));

// ---------------------------------------------------------------------------
// R7 accounting: total 102.2 = 83.7 (harness poison fills, untouchable; they
// also evict L3 every iter -> ~43MB/pass re-fetched from HBM) + fused ~13
// + finisher ~2.5 + gaps. Fused's overlapped floor ~9 us; VGPR=48 showed the
// compiler kept only ONE row-load in flight -> exposed L3 latency.
//
// This round: 2 rows per iteration with all 4 row-loads (pre r+1, pre r+2,
// gt r, gt r+1) issued back-to-back before the two stencil bodies -> 2x MLP
// per wave. __launch_bounds__(192,6) caps VGPR ~84 so the full 1552-block
// grid stays co-resident (6.1 blocks/CU, needs <=8). Finisher: one wave.
//
// Reduction: per-block plain store to d_ws (no same-address atomics — R7
// showed those cost ~10ns/block serialized); 1-wave finisher reduces and
// plain-stores d_out (sole writer overwrites the 0xAA poison; no memset).
// ---------------------------------------------------------------------------
__global__ __launch_bounds__(QW, 6) void fused_kernel(
    const float* __restrict__ pre,
    const float* __restrict__ gt,
    const int* __restrict__ cors,   // (B, K, 2) as [x, y]
    float* __restrict__ partials) { // d_ws: one slot per block

    __shared__ int   table[1024];   // corr-path hash table
    __shared__ float red[3];        // 192 threads = 3 waves

    const int lane = threadIdx.x & 63;
    float acc = 0.0f;

    if (blockIdx.x >= NCORRB) {
        // ---------------- strip stencil path ----------------
        const int sid   = blockIdx.x - NCORRB;
        const int b     = sid / STRIPS;
        const int strip = sid % STRIPS;
        const int r0    = strip * STRIP;
        const int t     = threadIdx.x;          // quad-column index [0,192)

        const float* preb = pre + b * HW;
        const float* gtb  = gt  + b * HW;

        int idx = r0 * WDIM + t * 4;            // element index of row r, col 4t

        f4v u4 = (r0 > 0) ? *(const f4v*)(preb + idx - WDIM)
                          : (f4v){0.f, 0.f, 0.f, 0.f};
        f4v c4 = *(const f4v*)(preb + idx);

        // one stencil row given center c, up u, down d, gt g (idx = row base)
        auto body = [&](const f4v& u, const f4v& c, const f4v& d, const f4v& g,
                        int rowidx) {
            const float lw = __shfl_up(c[3], 1);
            const float rx = __shfl_down(c[0], 1);
            float lft = lw, rgt = rx;
            if (lane == 0)  lft = (t > 0)      ? preb[rowidx - 1] : 0.0f;
            if (lane == 63) rgt = (t < QW - 1) ? preb[rowidx + 4] : 0.0f;

            const float lr[6] = {lft, c[0], c[1], c[2], c[3], rgt};
            #pragma unroll
            for (int j = 0; j < 4; ++j) {
                const bool peak = (c[j] > lr[j]) && (c[j] > lr[j + 2]) &&
                                  (c[j] > u[j]) && (c[j] > d[j]);
                float e = c[j] - g[j];
                e *= e;
                const float wt = (g[j] > 0.0f ? 5.0f : 1.0f) + (peak ? 1.0f : 0.0f);
                acc += wt * e;
            }
        };

        const int hot_pairs = (strip != STRIPS - 1) ? (STRIP / 2) : (STRIP / 2 - 1);
        #pragma unroll 4
        for (int k = 0; k < hot_pairs; ++k) {
            // issue all 4 row-loads back-to-back (2x MLP), then compute
            const f4v p1 = *(const f4v*)(preb + idx + WDIM);      // row r+1
            const f4v p2 = *(const f4v*)(preb + idx + 2 * WDIM);  // row r+2
            const f4v g1 = *(const f4v*)(gtb + idx);              // gt row r
            const f4v g2 = *(const f4v*)(gtb + idx + WDIM);       // gt row r+1

            body(u4, c4, p1, g1, idx);
            body(c4, p1, p2, g2, idx + WDIM);

            u4 = p1;
            c4 = p2;
            idx += 2 * WDIM;
        }
        if (strip == STRIPS - 1) {
            // image-bottom pair: rows 766, 767 (row 767's down-neighbor = 0)
            const f4v p1 = *(const f4v*)(preb + idx + WDIM);      // row 767
            const f4v g1 = *(const f4v*)(gtb + idx);
            const f4v g2 = *(const f4v*)(gtb + idx + WDIM);
            body(u4, c4, p1, g1, idx);
            body(c4, p1, (f4v){0.f, 0.f, 0.f, 0.f}, g2, idx + WDIM);
        }
    } else {
        // ---------------- correction path ----------------
        const int b = blockIdx.x;

        for (int i = threadIdx.x; i < 1024; i += QW) table[i] = -1;
        __syncthreads();

        for (int k = threadIdx.x; k < KCOR; k += QW) {
            const int x = cors[(b * KCOR + k) * 2 + 0];
            const int y = cors[(b * KCOR + k) * 2 + 1];
            const int packed = y * WDIM + x;

            // linear-probe insert; the CAS winner contributes (duplicates
            // give identical contributions, so any single winner is correct).
            unsigned h = ((unsigned)packed * 2654435761u) >> 22;   // 10 bits
            bool mine = false;
            for (;;) {
                const int old = atomicCAS(&table[h], -1, packed);
                if (old == -1)     { mine = true; break; }
                if (old == packed) { break; }
                h = (h + 1) & 1023;
            }

            if (mine) {
                const int idx = b * HW + packed;
                const float c = pre[idx];
                const float l = (x > 0)        ? pre[idx - 1]    : 0.0f;
                const float r = (x < WDIM - 1) ? pre[idx + 1]    : 0.0f;
                const float u = (y > 0)        ? pre[idx - WDIM] : 0.0f;
                const float d = (y < HDIM - 1) ? pre[idx + WDIM] : 0.0f;
                const bool peak = (c > l) && (c > r) && (c > u) && (c > d);
                float e = c - gt[idx];
                e *= e;
                acc += (peak ? -1.0f : 1.0f) * e;
            }
        }
    }

    // ---------------- block reduction, plain-store partial ----------------
    #pragma unroll
    for (int off = 32; off > 0; off >>= 1) acc += __shfl_down(acc, off);

    const int wave = threadIdx.x >> 6;
    if (lane == 0) red[wave] = acc;
    __syncthreads();
    if (threadIdx.x == 0) {
        partials[blockIdx.x] = red[0] + red[1] + red[2];   // no atomic
    }
}

// ---------------------------------------------------------------------------
// Finisher: ONE wave reduces the NBLK partials, plain-stores the scalar
// (sole writer of d_out -> overwrites the harness poison; no LDS/barrier).
// ---------------------------------------------------------------------------
__global__ __launch_bounds__(64) void finish_kernel(
    const float* __restrict__ partials,
    float* __restrict__ out) {

    float s = 0.0f;
    for (int i = threadIdx.x; i < NBLK; i += 64) s += partials[i];

    #pragma unroll
    for (int off = 32; off > 0; off >>= 1) s += __shfl_down(s, off);

    if (threadIdx.x == 0) out[0] = s * (1.0f / (float)BDIM);
}

extern "C" void kernel_launch(void* const* d_in, const int* in_sizes, int n_in,
                              void* d_out, int out_size, void* d_ws, size_t ws_size,
                              hipStream_t stream) {
    const float* pre  = (const float*)d_in[0];   // (16,1,768,768) fp32
    const float* gt   = (const float*)d_in[1];   // (16,1,768,768) fp32
    const int*   cors = (const int*)d_in[2];     // (16,512,2) int32

    float* out      = (float*)d_out;             // single fp32 scalar
    float* partials = (float*)d_ws;              // NBLK * 4 bytes used

    // Main pass: 16 corr blocks first, then 1536 strip blocks. Partials to ws.
    fused_kernel<<<NBLK, QW, 0, stream>>>(pre, gt, cors, partials);
    // Finisher: single wave reduces partials -> out (overwrites poison).
    finish_kernel<<<1, 64, 0, stream>>>(partials, out);
}

// Round 9
// 107.148 us; speedup vs baseline: 1.0158x; 1.0158x over previous
//
#include <hip/hip_runtime.h>

// Problem constants (from reference): B=16, C=1, H=768, W=768, K=512
#define BDIM 16
#define HDIM 768
#define WDIM 768
#define KCOR 512
#define STRIP 8                           // rows per strip block
constexpr int HW = HDIM * WDIM;           // 589824
constexpr int QW = WDIM / 4;              // 192 float4 quads per row (= block size)
constexpr int STRIPS = HDIM / STRIP;      // 96 strips per image
constexpr int NSTRIPB = BDIM * STRIPS;    // 1536 strip blocks
constexpr int NCORRB = BDIM;              // 16 corr blocks (first in grid)
constexpr int NBLK = NSTRIPB + NCORRB;    // 1552 total

typedef float f4v __attribute__((ext_vector_type(4)));

// ---------------------------------------------------------------------------
// R9 = exact revert to the R7 winner (102.2 us measured).
// Session ledger: total = ~83.7us harness poison fills (2x256MiB, untouchable,
// also flush LLC every iter) + fused ~13us + finisher ~2.5us + gaps ~3us.
// Both MLP-deepening attempts regressed (R4 +17us, R8 +6.6us): extra in-flight
// rows cost more in regalloc/scheduling than they hide in latency. R7's
// one-row body (VGPR=48, ~4.5 waves/SIMD, unconditional d-row load) is the
// practical floor for this structure.
//
// Structure:
//  * single fused main dispatch, heterogeneous blocks:
//      blocks [0,16):    per-image gt-coordinate XOR correction, LDS-hash
//                        dedup via atomicCAS (duplicates contribute
//                        identically -> any single winner is correct)
//      blocks [16,1552): 8-row strip stencil, row-walk with up/center rows
//                        in registers, left/right via wave shuffle
//  * per-block partial PLAIN-STORED to d_ws (same-address device atomics
//    serialize ~10ns/block at the TCC -> removed entirely, R7: -14us)
//  * 1-wave finisher reduces 1552 partials, plain-stores d_out (sole
//    writer overwrites the 0xAA poison; no memset dispatch needed)
// ---------------------------------------------------------------------------
__global__ __launch_bounds__(QW, 4) void fused_kernel(
    const float* __restrict__ pre,
    const float* __restrict__ gt,
    const int* __restrict__ cors,   // (B, K, 2) as [x, y]
    float* __restrict__ partials) { // d_ws: one slot per block

    __shared__ int   table[1024];   // corr-path hash table
    __shared__ float red[3];        // 192 threads = 3 waves

    const int lane = threadIdx.x & 63;
    float acc = 0.0f;

    if (blockIdx.x >= NCORRB) {
        // ---------------- strip stencil path ----------------
        const int sid   = blockIdx.x - NCORRB;
        const int b     = sid / STRIPS;
        const int strip = sid % STRIPS;
        const int r0    = strip * STRIP;
        const int t     = threadIdx.x;          // quad-column index [0,192)

        const float* preb = pre + b * HW;
        const float* gtb  = gt  + b * HW;

        int idx = r0 * WDIM + t * 4;

        f4v u4 = (r0 > 0) ? *(const f4v*)(preb + idx - WDIM)
                          : (f4v){0.f, 0.f, 0.f, 0.f};
        f4v c4 = *(const f4v*)(preb + idx);

        // one row-step given this row's down-neighbor row and gt row
        auto body = [&](f4v d4, f4v g4) {
            // left/right via intra-wave shuffle of the center row;
            // wave-boundary lanes fall back to an L1-hit scalar load.
            const float lw = __shfl_up(c4[3], 1);
            const float rx = __shfl_down(c4[0], 1);
            float lft = lw, rgt = rx;
            if (lane == 0)  lft = (t > 0)      ? preb[idx - 1] : 0.0f;
            if (lane == 63) rgt = (t < QW - 1) ? preb[idx + 4] : 0.0f;

            const float lr[6] = {lft, c4[0], c4[1], c4[2], c4[3], rgt};
            #pragma unroll
            for (int j = 0; j < 4; ++j) {
                const bool peak = (c4[j] > lr[j]) && (c4[j] > lr[j + 2]) &&
                                  (c4[j] > u4[j]) && (c4[j] > d4[j]);
                float e = c4[j] - g4[j];
                e *= e;
                const float wt = (g4[j] > 0.0f ? 5.0f : 1.0f) + (peak ? 1.0f : 0.0f);
                acc += wt * e;
            }
            u4 = c4;
            c4 = d4;
            idx += WDIM;
        };

        if (strip != STRIPS - 1) {
            // hot path: all 8 down-rows exist -> unconditional, pipelineable.
            #pragma unroll 4
            for (int r = 0; r < STRIP; ++r) {
                const f4v d4 = *(const f4v*)(preb + idx + WDIM);
                const f4v g4 = *(const f4v*)(gtb + idx);
                body(d4, g4);
            }
        } else {
            // image-bottom strip: 7 unconditional rows + explicit tail.
            #pragma unroll 4
            for (int r = 0; r < STRIP - 1; ++r) {
                const f4v d4 = *(const f4v*)(preb + idx + WDIM);
                const f4v g4 = *(const f4v*)(gtb + idx);
                body(d4, g4);
            }
            const f4v g4 = *(const f4v*)(gtb + idx);
            body((f4v){0.f, 0.f, 0.f, 0.f}, g4);
        }
    } else {
        // ---------------- correction path ----------------
        const int b = blockIdx.x;

        for (int i = threadIdx.x; i < 1024; i += QW) table[i] = -1;
        __syncthreads();

        for (int k = threadIdx.x; k < KCOR; k += QW) {
            const int x = cors[(b * KCOR + k) * 2 + 0];
            const int y = cors[(b * KCOR + k) * 2 + 1];
            const int packed = y * WDIM + x;

            // linear-probe insert; the CAS winner contributes (duplicates
            // give identical contributions, so any single winner is correct).
            unsigned h = ((unsigned)packed * 2654435761u) >> 22;   // 10 bits
            bool mine = false;
            for (;;) {
                const int old = atomicCAS(&table[h], -1, packed);
                if (old == -1)     { mine = true; break; }
                if (old == packed) { break; }
                h = (h + 1) & 1023;
            }

            if (mine) {
                const int idx = b * HW + packed;
                const float c = pre[idx];
                const float l = (x > 0)        ? pre[idx - 1]    : 0.0f;
                const float r = (x < WDIM - 1) ? pre[idx + 1]    : 0.0f;
                const float u = (y > 0)        ? pre[idx - WDIM] : 0.0f;
                const float d = (y < HDIM - 1) ? pre[idx + WDIM] : 0.0f;
                const bool peak = (c > l) && (c > r) && (c > u) && (c > d);
                float e = c - gt[idx];
                e *= e;
                acc += (peak ? -1.0f : 1.0f) * e;
            }
        }
    }

    // ---------------- block reduction, plain-store partial ----------------
    #pragma unroll
    for (int off = 32; off > 0; off >>= 1) acc += __shfl_down(acc, off);

    const int wave = threadIdx.x >> 6;
    if (lane == 0) red[wave] = acc;
    __syncthreads();
    if (threadIdx.x == 0) {
        partials[blockIdx.x] = red[0] + red[1] + red[2];   // no atomic
    }
}

// ---------------------------------------------------------------------------
// Finisher: ONE wave reduces the NBLK partials, plain-stores the scalar
// (sole writer of d_out -> overwrites the harness poison; no LDS/barrier).
// ---------------------------------------------------------------------------
__global__ __launch_bounds__(64) void finish_kernel(
    const float* __restrict__ partials,
    float* __restrict__ out) {

    float s = 0.0f;
    for (int i = threadIdx.x; i < NBLK; i += 64) s += partials[i];

    #pragma unroll
    for (int off = 32; off > 0; off >>= 1) s += __shfl_down(s, off);

    if (threadIdx.x == 0) out[0] = s * (1.0f / (float)BDIM);
}

extern "C" void kernel_launch(void* const* d_in, const int* in_sizes, int n_in,
                              void* d_out, int out_size, void* d_ws, size_t ws_size,
                              hipStream_t stream) {
    const float* pre  = (const float*)d_in[0];   // (16,1,768,768) fp32
    const float* gt   = (const float*)d_in[1];   // (16,1,768,768) fp32
    const int*   cors = (const int*)d_in[2];     // (16,512,2) int32

    float* out      = (float*)d_out;             // single fp32 scalar
    float* partials = (float*)d_ws;              // NBLK * 4 bytes used

    // Main pass: 16 corr blocks first, then 1536 strip blocks. Partials to ws.
    fused_kernel<<<NBLK, QW, 0, stream>>>(pre, gt, cors, partials);
    // Finisher: single wave reduces partials -> out (overwrites poison).
    finish_kernel<<<1, 64, 0, stream>>>(partials, out);
}